// Round 2
// baseline (4244.670 us; speedup 1.0000x reference)
//
#include <hip/hip_runtime.h>

// Problem: 2-layer LSTM (H1=128, H2=64, T=128, D_IN=2, B=2048) + FC(8192->11), fp32.
// Strategy: register-persistent weights (2-kernel split), xor-indexed batch
// accumulators reduced with DPP quad-perm + ds_swizzle, conflict-free LDS layouts.

#define TSTEPS 128
#define NCLS 11

// ws float-index layout:
//   wsA  [1024][64]  per-thread L1 weights            @ 0
//   wsB  [1024][48]  per-thread L2 weights            @ 65536
//   wsC  [8192][12]  Wfc transposed (+1 pad col)      @ 114688
//   h1s  [128][2048][128] layer-1 hidden states       @ 212992
#define WSA_OFF 0
#define WSB_OFF 65536
#define WSC_OFF 114688
#define H1S_OFF 212992

__device__ __forceinline__ float sigm(float x) { return 1.0f / (1.0f + __expf(-x)); }
__device__ __forceinline__ float tanh_(float x) { return 1.0f - 2.0f / (__expf(2.0f * x) + 1.0f); }

template<int C> __device__ __forceinline__ float dppmov(float v) {
    union { float f; int i; } u, r; u.f = v;
    r.i = __builtin_amdgcn_update_dpp(0, u.i, C, 0xf, 0xf, true);
    return r.f;
}
template<int P> __device__ __forceinline__ float swzl(float v) {
    union { float f; int i; } u, r; u.f = v;
    r.i = __builtin_amdgcn_ds_swizzle(u.i, P);
    return r.f;
}
// Accs indexed j with b = j ^ (lane&7). Returns, at lane with ks=lane&7, the
// total over all 8 ks lanes for b = ks. 0xB1 = quad_perm xor1, 0x4E = xor2,
// 0x101F = ds_swizzle xor4.
__device__ __forceinline__ float xred8(float a0, float a1, float a2, float a3,
                                       float a4, float a5, float a6, float a7) {
    a0 += dppmov<0xB1>(a1);
    a2 += dppmov<0xB1>(a3);
    a4 += dppmov<0xB1>(a5);
    a6 += dppmov<0xB1>(a7);
    a0 += dppmov<0x4E>(a2);
    a4 += dppmov<0x4E>(a6);
    return a0 + swzl<0x101F>(a4);
}

// ---------------- prep: repack weights into per-thread layouts ----------------
__global__ void prep(const float* __restrict__ Whh1, const float* __restrict__ Wih2,
                     const float* __restrict__ Whh2, const float* __restrict__ Wfc,
                     float* __restrict__ ws) {
    int o = blockIdx.x * blockDim.x + threadIdx.x;
    if (o < 65536) {
        // wsA[tid][i]: tid=(d<<3)|ks, i=(g<<4)|j  -> Whh1[g*128+d][ks*16+j]
        int i = o & 63, tt = o >> 6;
        int ks = tt & 7, d = tt >> 3;
        int j = i & 15, g = i >> 4;
        ws[WSA_OFF + o] = Whh1[(g * 128 + d) * 128 + ks * 16 + j];
    } else if (o < 114688) {
        // wsB[tid][i]: tid=(d2<<4)|ks; i<32: Wih2 g=i>>3,j=i&7; else Whh2 g,j of 4
        int p = o - 65536;
        int tt = p / 48, i = p % 48;
        int ks = tt & 15, d2 = tt >> 4;
        float v;
        if (i < 32) { int g = i >> 3, j = i & 7; v = Wih2[(g * 64 + d2) * 128 + ks * 8 + j]; }
        else { int i2 = i - 32; int g = i2 >> 2, j = i2 & 3; v = Whh2[(g * 64 + d2) * 64 + ks * 4 + j]; }
        ws[WSB_OFF + p] = v;
    } else if (o < 212992) {
        int p = o - 114688;
        int r = p / 12, c = p % 12;
        ws[WSC_OFF + p] = (c < NCLS) ? Wfc[c * 8192 + r] : 0.0f;
    }
}

// ---------------- kernel A: layer-1 LSTM, weights in registers ----------------
// grid 256 x 1024. thread = (d = tid>>3, ks = tid&7); 8 batches/block.
// acc[j][g] accumulates gate g, batch b = j^ks, over k-slice [ks*16, ks*16+16).
__global__ __launch_bounds__(1024, 4) void lstm_l1(
    const float* __restrict__ x, const float* __restrict__ Wih1,
    float* __restrict__ ws) {
    __shared__ __align__(16) float lx[8 * 257];   // [b][c*128+t], pad 257 (bank-free)
    __shared__ __align__(16) float lh1[8 * 132];  // [b][128+4pad], stride 132

    const int tid = threadIdx.x;
    const int ks = tid & 7, d = tid >> 3;
    const int b0 = blockIdx.x * 8;

    // persistent weights: W[g][ks*16+jc*4 .. +4] = wv[g*4+jc]
    float4 wv[16];
    const float4* wsrc = (const float4*)(ws + WSA_OFF) + tid * 16;
#pragma unroll
    for (int i = 0; i < 16; ++i) wv[i] = wsrc[i];

    // input-projection weights for my d (gate order i,f,g,o)
    const float wi0 = Wih1[(0 * 128 + d) * 2], wi1 = Wih1[(0 * 128 + d) * 2 + 1];
    const float wf0 = Wih1[(1 * 128 + d) * 2], wf1 = Wih1[(1 * 128 + d) * 2 + 1];
    const float wg0 = Wih1[(2 * 128 + d) * 2], wg1 = Wih1[(2 * 128 + d) * 2 + 1];
    const float wo0 = Wih1[(3 * 128 + d) * 2], wo1 = Wih1[(3 * 128 + d) * 2 + 1];

    for (int i = tid; i < 8 * 256; i += 1024) {
        int b = i >> 8, r = i & 255;
        lx[b * 257 + r] = x[(b0 + b) * 256 + r];
    }
    for (int i = tid; i < 8 * 132; i += 1024) lh1[i] = 0.0f;

    // hoisted LDS byte-offsets: lh1[(j^ks)][ks*16 + ...]
    int off[8];
#pragma unroll
    for (int j = 0; j < 8; ++j) off[j] = (j ^ ks) * 528 + ks * 64;
    const char* lh1b = (const char*)lh1;
    const int lxb = ks * 257;

    float* __restrict__ h1s = ws + H1S_OFF;
    float c1 = 0.0f;
    __syncthreads();

    for (int t = 0; t < TSTEPS; ++t) {
        float acc[8][4];
#pragma unroll
        for (int j = 0; j < 8; ++j)
#pragma unroll
            for (int g = 0; g < 4; ++g) acc[j][g] = 0.0f;

#pragma unroll
        for (int jc = 0; jc < 4; ++jc) {
#pragma unroll
            for (int j = 0; j < 8; ++j) {
                const float4 h = *(const float4*)(lh1b + off[j] + jc * 16);
#pragma unroll
                for (int g = 0; g < 4; ++g) {
                    const float4 w4 = wv[g * 4 + jc];
                    acc[j][g] += h.x * w4.x + h.y * w4.y + h.z * w4.z + h.w * w4.w;
                }
            }
        }
        // reduce over ks; this lane now owns batch b = ks
        float gi = xred8(acc[0][0], acc[1][0], acc[2][0], acc[3][0], acc[4][0], acc[5][0], acc[6][0], acc[7][0]);
        float gf = xred8(acc[0][1], acc[1][1], acc[2][1], acc[3][1], acc[4][1], acc[5][1], acc[6][1], acc[7][1]);
        float gg = xred8(acc[0][2], acc[1][2], acc[2][2], acc[3][2], acc[4][2], acc[5][2], acc[6][2], acc[7][2]);
        float go = xred8(acc[0][3], acc[1][3], acc[2][3], acc[3][3], acc[4][3], acc[5][3], acc[6][3], acc[7][3]);

        const float x0 = lx[lxb + t], x1 = lx[lxb + 128 + t];
        gi += wi0 * x0 + wi1 * x1;
        gf += wf0 * x0 + wf1 * x1;
        gg += wg0 * x0 + wg1 * x1;
        go += wo0 * x0 + wo1 * x1;

        const float i1 = sigm(gi), f1 = sigm(gf), g1 = tanh_(gg), o1 = sigm(go);
        c1 = f1 * c1 + i1 * g1;
        const float h1n = o1 * tanh_(c1);

        __syncthreads();                       // all reads of old lh1 done
        lh1[ks * 132 + d] = h1n;
        h1s[(t * 2048 + b0 + ks) * 128 + d] = h1n;
        __syncthreads();                       // new lh1 visible
    }
}

// ---------------- kernel B: layer-2 LSTM + fused FC ----------------
// grid 256 x 1024. thread = (d2 = tid>>4, ks = tid&15); K=192 split 12/thread
// (8 from h1, 4 from h2). acc[j][g]: b = j ^ (ks&7).
__global__ __launch_bounds__(1024, 4) void lstm_l2(
    const float* __restrict__ bfc, float* __restrict__ ws, float* __restrict__ out) {
    __shared__ __align__(16) float lh1t[2 * 8 * 132]; // double-buffered staged h1[t]
    __shared__ __align__(16) float lh2[8 * 64];
    __shared__ __align__(16) float gfc[16 * 88];

    const int tid = threadIdx.x;
    const int ks = tid & 15, ksl = ks & 7, d2 = tid >> 4;
    const int b0 = blockIdx.x * 8;
    const float* __restrict__ h1s = ws + H1S_OFF;
    const float* __restrict__ wsc = ws + WSC_OFF;

    // persistent weights: wv[g*2+jc] = Wih2[g*64+d2][ks*8+jc*4..], wv[8+g] = Whh2[..][ks*4..]
    float4 wv[12];
    const float4* wsrc = (const float4*)(ws + WSB_OFF) + tid * 12;
#pragma unroll
    for (int i = 0; i < 12; ++i) wv[i] = wsrc[i];

    for (int i = tid; i < 8 * 64; i += 1024) lh2[i] = 0.0f;

    int off1[8], off2[8];
#pragma unroll
    for (int j = 0; j < 8; ++j) {
        off1[j] = (j ^ ksl) * 528 + ks * 32;   // lh1t row stride 132 floats
        off2[j] = (j ^ ksl) * 256 + ks * 16;   // lh2 row stride 64 floats
    }
    const char* lh1tb = (const char*)lh1t;
    const char* lh2b = (const char*)lh2;

    // stage t=0
    const int k4 = tid & 31, bs = tid >> 5;
    if (tid < 256)
        *(float4*)((char*)lh1t + (bs * 33 + k4) * 16) =
            *(const float4*)(h1s + (b0 + bs) * 128 + k4 * 4);

    float c2 = 0.0f;
    float facc[NCLS];
#pragma unroll
    for (int c = 0; c < NCLS; ++c) facc[c] = 0.0f;
    __syncthreads();

    auto step = [&](int t, int bufoff, int nbufoff) {
        // prefetch next h1 tile (global -> regs), commit to LDS after barrier
        float4 stg;
        const bool do_stage = (t < TSTEPS - 1) && (tid < 256);
        if (do_stage)
            stg = *(const float4*)(h1s + ((t + 1) * 2048 + b0 + bs) * 128 + k4 * 4);

        float acc[8][4];
#pragma unroll
        for (int j = 0; j < 8; ++j)
#pragma unroll
            for (int g = 0; g < 4; ++g) acc[j][g] = 0.0f;

#pragma unroll
        for (int jc = 0; jc < 2; ++jc) {
#pragma unroll
            for (int j = 0; j < 8; ++j) {
                const float4 h = *(const float4*)(lh1tb + bufoff + off1[j] + jc * 16);
#pragma unroll
                for (int g = 0; g < 4; ++g) {
                    const float4 w4 = wv[g * 2 + jc];
                    acc[j][g] += h.x * w4.x + h.y * w4.y + h.z * w4.z + h.w * w4.w;
                }
            }
        }
#pragma unroll
        for (int j = 0; j < 8; ++j) {
            const float4 h = *(const float4*)(lh2b + off2[j]);
#pragma unroll
            for (int g = 0; g < 4; ++g) {
                const float4 w4 = wv[8 + g];
                acc[j][g] += h.x * w4.x + h.y * w4.y + h.z * w4.z + h.w * w4.w;
            }
        }
        // reduce over 16 ks lanes (octet tree + xor8); lane owns b = ksl
        float gi = xred8(acc[0][0], acc[1][0], acc[2][0], acc[3][0], acc[4][0], acc[5][0], acc[6][0], acc[7][0]);
        float gf = xred8(acc[0][1], acc[1][1], acc[2][1], acc[3][1], acc[4][1], acc[5][1], acc[6][1], acc[7][1]);
        float gg = xred8(acc[0][2], acc[1][2], acc[2][2], acc[3][2], acc[4][2], acc[5][2], acc[6][2], acc[7][2]);
        float go = xred8(acc[0][3], acc[1][3], acc[2][3], acc[3][3], acc[4][3], acc[5][3], acc[6][3], acc[7][3]);
        gi += swzl<0x201F>(gi);
        gf += swzl<0x201F>(gf);
        gg += swzl<0x201F>(gg);
        go += swzl<0x201F>(go);

        const float i2 = sigm(gi), f2 = sigm(gf), g2 = tanh_(gg), o2 = sigm(go);
        c2 = f2 * c2 + i2 * g2;
        const float h2n = o2 * tanh_(c2);

        if (ks < 8) {  // unique (b=ks, d2) owner accumulates FC
            const float4* wq = (const float4*)(wsc + (t * 64 + d2) * 12);
            const float4 q0 = wq[0], q1 = wq[1], q2 = wq[2];
            facc[0] += h2n * q0.x; facc[1] += h2n * q0.y; facc[2] += h2n * q0.z; facc[3] += h2n * q0.w;
            facc[4] += h2n * q1.x; facc[5] += h2n * q1.y; facc[6] += h2n * q1.z; facc[7] += h2n * q1.w;
            facc[8] += h2n * q2.x; facc[9] += h2n * q2.y; facc[10] += h2n * q2.z;
        }
        __syncthreads();                       // reads of lh1t[buf], lh2 done
        if (do_stage)
            *(float4*)((char*)lh1t + nbufoff + (bs * 33 + k4) * 16) = stg;
        lh2[ksl * 64 + d2] = h2n;              // ks and ks+8 write identical value
        __syncthreads();                       // staged tile + new lh2 visible
    };

    for (int th = 0; th < TSTEPS / 2; ++th) {
        step(2 * th, 0, 4224);
        step(2 * th + 1, 4224, 0);
    }

    // FC reduction: sum facc over the wave's 4 d2 values (lane bits 4,5)
#pragma unroll
    for (int c = 0; c < NCLS; ++c) {
        float v = facc[c];
        v += __shfl_xor(v, 16);
        v += __shfl_xor(v, 32);
        facc[c] = v;
    }
    const int w = tid >> 6;
    if ((tid & 63) < 8) {                      // lane = ks < 8, d2-subgroup 0
#pragma unroll
        for (int c = 0; c < NCLS; ++c) gfc[w * 88 + ks * 11 + c] = facc[c];
    }
    __syncthreads();
    if (tid < 88) {
        const int b = tid / 11, c = tid % 11;
        float s = bfc[c];
#pragma unroll
        for (int w2 = 0; w2 < 16; ++w2) s += gfc[w2 * 88 + b * 11 + c];
        out[(b0 + b) * 11 + c] = s;
    }
}

extern "C" void kernel_launch(void* const* d_in, const int* in_sizes, int n_in,
                              void* d_out, int out_size, void* d_ws, size_t ws_size,
                              hipStream_t stream) {
    const float* x    = (const float*)d_in[0];
    const float* Wih1 = (const float*)d_in[1];
    const float* Whh1 = (const float*)d_in[2];
    const float* Wih2 = (const float*)d_in[3];
    const float* Whh2 = (const float*)d_in[4];
    const float* Wfc  = (const float*)d_in[5];
    const float* bfc  = (const float*)d_in[6];
    float* out = (float*)d_out;
    float* ws  = (float*)d_ws;

    prep<<<(212992 + 255) / 256, 256, 0, stream>>>(Whh1, Wih2, Whh2, Wfc, ws);
    lstm_l1<<<256, 1024, 0, stream>>>(x, Wih1, ws);
    lstm_l2<<<256, 1024, 0, stream>>>(bfc, ws, out);
}

// Round 3
// 3767.558 us; speedup vs baseline: 1.1266x; 1.1266x over previous
//
#include <hip/hip_runtime.h>

// Problem: 2-layer LSTM (H1=128, H2=64, T=128, D_IN=2, B=2048) + FC(8192->11), fp32.
// Strategy: register-persistent weights (2-kernel split), xor-indexed batch
// accumulators reduced with DPP quad-perm + ds_swizzle, conflict-free LDS layouts.
// R3: asm-pin weight registers (R2 spilled: compiler chose VGPR=64 and re-fetched
// 8.6 GB/dispatch of weights); coalesced h1s stores via LDS round-trip.

#define TSTEPS 128
#define NCLS 11

// ws float-index layout:
//   wsA  [1024][64]  per-thread L1 weights            @ 0
//   wsB  [1024][48]  per-thread L2 weights            @ 65536
//   wsC  [8192][12]  Wfc transposed (+1 pad col)      @ 114688
//   h1s  [128][2048][128] layer-1 hidden states       @ 212992
#define WSA_OFF 0
#define WSB_OFF 65536
#define WSC_OFF 114688
#define H1S_OFF 212992

__device__ __forceinline__ float sigm(float x) { return 1.0f / (1.0f + __expf(-x)); }
__device__ __forceinline__ float tanh_(float x) { return 1.0f - 2.0f / (__expf(2.0f * x) + 1.0f); }

#define PIN4(v) asm volatile("" : "+v"((v).x), "+v"((v).y), "+v"((v).z), "+v"((v).w))

template<int C> __device__ __forceinline__ float dppmov(float v) {
    union { float f; int i; } u, r; u.f = v;
    r.i = __builtin_amdgcn_update_dpp(0, u.i, C, 0xf, 0xf, true);
    return r.f;
}
template<int P> __device__ __forceinline__ float swzl(float v) {
    union { float f; int i; } u, r; u.f = v;
    r.i = __builtin_amdgcn_ds_swizzle(u.i, P);
    return r.f;
}
// Accs indexed j with b = j ^ (lane&7). Returns, at lane with ks=lane&7, the
// total over all 8 ks lanes for b = ks. 0xB1 = quad_perm xor1, 0x4E = xor2,
// 0x101F = ds_swizzle xor4.
__device__ __forceinline__ float xred8(float a0, float a1, float a2, float a3,
                                       float a4, float a5, float a6, float a7) {
    a0 += dppmov<0xB1>(a1);
    a2 += dppmov<0xB1>(a3);
    a4 += dppmov<0xB1>(a5);
    a6 += dppmov<0xB1>(a7);
    a0 += dppmov<0x4E>(a2);
    a4 += dppmov<0x4E>(a6);
    return a0 + swzl<0x101F>(a4);
}

// ---------------- prep: repack weights into per-thread layouts ----------------
__global__ void prep(const float* __restrict__ Whh1, const float* __restrict__ Wih2,
                     const float* __restrict__ Whh2, const float* __restrict__ Wfc,
                     float* __restrict__ ws) {
    int o = blockIdx.x * blockDim.x + threadIdx.x;
    if (o < 65536) {
        // wsA[tid][i]: tid=(d<<3)|ks, i=(g<<4)|j  -> Whh1[g*128+d][ks*16+j]
        int i = o & 63, tt = o >> 6;
        int ks = tt & 7, d = tt >> 3;
        int j = i & 15, g = i >> 4;
        ws[WSA_OFF + o] = Whh1[(g * 128 + d) * 128 + ks * 16 + j];
    } else if (o < 114688) {
        // wsB[tid][i]: tid=(d2<<4)|ks; i<32: Wih2 g=i>>3,j=i&7; else Whh2 g,j of 4
        int p = o - 65536;
        int tt = p / 48, i = p % 48;
        int ks = tt & 15, d2 = tt >> 4;
        float v;
        if (i < 32) { int g = i >> 3, j = i & 7; v = Wih2[(g * 64 + d2) * 128 + ks * 8 + j]; }
        else { int i2 = i - 32; int g = i2 >> 2, j = i2 & 3; v = Whh2[(g * 64 + d2) * 64 + ks * 4 + j]; }
        ws[WSB_OFF + p] = v;
    } else if (o < 212992) {
        int p = o - 114688;
        int r = p / 12, c = p % 12;
        ws[WSC_OFF + p] = (c < NCLS) ? Wfc[c * 8192 + r] : 0.0f;
    }
}

// ---------------- kernel A: layer-1 LSTM, weights in registers ----------------
// grid 256 x 1024. thread = (d = tid>>3, ks = tid&7); 8 batches/block.
// acc[j][g] accumulates gate g, batch b = j^ks, over k-slice [ks*16, ks*16+16).
__global__ __launch_bounds__(1024, 4) void lstm_l1(
    const float* __restrict__ x, const float* __restrict__ Wih1,
    float* __restrict__ ws) {
    __shared__ __align__(16) float lx[8 * 257];   // [b][c*128+t], pad 257 (bank-free)
    __shared__ __align__(16) float lh1[8 * 132];  // [b][128+4pad], stride 132

    const int tid = threadIdx.x;
    const int ks = tid & 7, d = tid >> 3;
    const int b0 = blockIdx.x * 8;

    // persistent weights: W[g][ks*16+jc*4 .. +4] = wv[g*4+jc]
    float4 wv[16];
    const float4* wsrc = (const float4*)(ws + WSA_OFF) + tid * 16;
#pragma unroll
    for (int i = 0; i < 16; ++i) wv[i] = wsrc[i];
#pragma unroll
    for (int i = 0; i < 16; ++i) PIN4(wv[i]);   // force register residency

    // input-projection weights for my d (gate order i,f,g,o)
    const float wi0 = Wih1[(0 * 128 + d) * 2], wi1 = Wih1[(0 * 128 + d) * 2 + 1];
    const float wf0 = Wih1[(1 * 128 + d) * 2], wf1 = Wih1[(1 * 128 + d) * 2 + 1];
    const float wg0 = Wih1[(2 * 128 + d) * 2], wg1 = Wih1[(2 * 128 + d) * 2 + 1];
    const float wo0 = Wih1[(3 * 128 + d) * 2], wo1 = Wih1[(3 * 128 + d) * 2 + 1];

    for (int i = tid; i < 8 * 256; i += 1024) {
        int b = i >> 8, r = i & 255;
        lx[b * 257 + r] = x[(b0 + b) * 256 + r];
    }
    for (int i = tid; i < 8 * 132; i += 1024) lh1[i] = 0.0f;

    // hoisted LDS byte-offsets: lh1[(j^ks)][ks*16 + ...]
    int off[8];
#pragma unroll
    for (int j = 0; j < 8; ++j) off[j] = (j ^ ks) * 528 + ks * 64;
    const char* lh1b = (const char*)lh1;
    const int lxb = ks * 257;

    float* __restrict__ h1s = ws + H1S_OFF;
    const int sread = (tid >> 7) * 132 + (tid & 127);  // coalesced store source
    float c1 = 0.0f;
    __syncthreads();

    for (int t = 0; t < TSTEPS; ++t) {
        float acc[8][4];
#pragma unroll
        for (int j = 0; j < 8; ++j)
#pragma unroll
            for (int g = 0; g < 4; ++g) acc[j][g] = 0.0f;

#pragma unroll
        for (int jc = 0; jc < 4; ++jc) {
#pragma unroll
            for (int j = 0; j < 8; ++j) {
                const float4 h = *(const float4*)(lh1b + off[j] + jc * 16);
#pragma unroll
                for (int g = 0; g < 4; ++g) {
                    const float4 w4 = wv[g * 4 + jc];
                    acc[j][g] += h.x * w4.x + h.y * w4.y + h.z * w4.z + h.w * w4.w;
                }
            }
        }
        // reduce over ks; this lane now owns batch b = ks
        float gi = xred8(acc[0][0], acc[1][0], acc[2][0], acc[3][0], acc[4][0], acc[5][0], acc[6][0], acc[7][0]);
        float gf = xred8(acc[0][1], acc[1][1], acc[2][1], acc[3][1], acc[4][1], acc[5][1], acc[6][1], acc[7][1]);
        float gg = xred8(acc[0][2], acc[1][2], acc[2][2], acc[3][2], acc[4][2], acc[5][2], acc[6][2], acc[7][2]);
        float go = xred8(acc[0][3], acc[1][3], acc[2][3], acc[3][3], acc[4][3], acc[5][3], acc[6][3], acc[7][3]);

        const float x0 = lx[lxb + t], x1 = lx[lxb + 128 + t];
        gi += wi0 * x0 + wi1 * x1;
        gf += wf0 * x0 + wf1 * x1;
        gg += wg0 * x0 + wg1 * x1;
        go += wo0 * x0 + wo1 * x1;

        const float i1 = sigm(gi), f1 = sigm(gf), g1 = tanh_(gg), o1 = sigm(go);
        c1 = f1 * c1 + i1 * g1;
        const float h1n = o1 * tanh_(c1);

        __syncthreads();                       // all reads of old lh1 done
        lh1[ks * 132 + d] = h1n;
        __syncthreads();                       // new lh1 visible
        // coalesced h1 dump: block tile is contiguous [b0*128, b0*128+1024)
        h1s[t * 262144 + b0 * 128 + tid] = lh1[sread];
    }
}

// ---------------- kernel B: layer-2 LSTM + fused FC ----------------
// grid 256 x 1024. thread = (d2 = tid>>4, ks = tid&15); K=192 split 12/thread
// (8 from h1, 4 from h2). acc[j][g]: b = j ^ (ks&7).
__global__ __launch_bounds__(1024, 4) void lstm_l2(
    const float* __restrict__ bfc, float* __restrict__ ws, float* __restrict__ out) {
    __shared__ __align__(16) float lh1t[2 * 8 * 132]; // double-buffered staged h1[t]
    __shared__ __align__(16) float lh2[8 * 64];
    __shared__ __align__(16) float gfc[16 * 88];

    const int tid = threadIdx.x;
    const int ks = tid & 15, ksl = ks & 7, d2 = tid >> 4;
    const int b0 = blockIdx.x * 8;
    const float* __restrict__ h1s = ws + H1S_OFF;
    const float* __restrict__ wsc = ws + WSC_OFF;

    // persistent weights: wv[g*2+jc] = Wih2[g*64+d2][ks*8+jc*4..], wv[8+g] = Whh2[..][ks*4..]
    float4 wv[12];
    const float4* wsrc = (const float4*)(ws + WSB_OFF) + tid * 12;
#pragma unroll
    for (int i = 0; i < 12; ++i) wv[i] = wsrc[i];
#pragma unroll
    for (int i = 0; i < 12; ++i) PIN4(wv[i]);   // force register residency

    for (int i = tid; i < 8 * 64; i += 1024) lh2[i] = 0.0f;

    int off1[8], off2[8];
#pragma unroll
    for (int j = 0; j < 8; ++j) {
        off1[j] = (j ^ ksl) * 528 + ks * 32;   // lh1t row stride 132 floats
        off2[j] = (j ^ ksl) * 256 + ks * 16;   // lh2 row stride 64 floats
    }
    const char* lh1tb = (const char*)lh1t;
    const char* lh2b = (const char*)lh2;

    // stage t=0
    const int k4 = tid & 31, bs = tid >> 5;
    if (tid < 256)
        *(float4*)((char*)lh1t + (bs * 33 + k4) * 16) =
            *(const float4*)(h1s + (b0 + bs) * 128 + k4 * 4);

    float c2 = 0.0f;
    float facc[NCLS];
#pragma unroll
    for (int c = 0; c < NCLS; ++c) facc[c] = 0.0f;
    __syncthreads();

    auto step = [&](int t, int bufoff, int nbufoff) {
        // prefetch next h1 tile (global -> regs), commit to LDS after barrier
        float4 stg;
        const bool do_stage = (t < TSTEPS - 1) && (tid < 256);
        if (do_stage)
            stg = *(const float4*)(h1s + ((t + 1) * 2048 + b0 + bs) * 128 + k4 * 4);

        float acc[8][4];
#pragma unroll
        for (int j = 0; j < 8; ++j)
#pragma unroll
            for (int g = 0; g < 4; ++g) acc[j][g] = 0.0f;

#pragma unroll
        for (int jc = 0; jc < 2; ++jc) {
#pragma unroll
            for (int j = 0; j < 8; ++j) {
                const float4 h = *(const float4*)(lh1tb + bufoff + off1[j] + jc * 16);
#pragma unroll
                for (int g = 0; g < 4; ++g) {
                    const float4 w4 = wv[g * 2 + jc];
                    acc[j][g] += h.x * w4.x + h.y * w4.y + h.z * w4.z + h.w * w4.w;
                }
            }
        }
#pragma unroll
        for (int j = 0; j < 8; ++j) {
            const float4 h = *(const float4*)(lh2b + off2[j]);
#pragma unroll
            for (int g = 0; g < 4; ++g) {
                const float4 w4 = wv[8 + g];
                acc[j][g] += h.x * w4.x + h.y * w4.y + h.z * w4.z + h.w * w4.w;
            }
        }
        // reduce over 16 ks lanes (octet tree + xor8); lane owns b = ksl
        float gi = xred8(acc[0][0], acc[1][0], acc[2][0], acc[3][0], acc[4][0], acc[5][0], acc[6][0], acc[7][0]);
        float gf = xred8(acc[0][1], acc[1][1], acc[2][1], acc[3][1], acc[4][1], acc[5][1], acc[6][1], acc[7][1]);
        float gg = xred8(acc[0][2], acc[1][2], acc[2][2], acc[3][2], acc[4][2], acc[5][2], acc[6][2], acc[7][2]);
        float go = xred8(acc[0][3], acc[1][3], acc[2][3], acc[3][3], acc[4][3], acc[5][3], acc[6][3], acc[7][3]);
        gi += swzl<0x201F>(gi);
        gf += swzl<0x201F>(gf);
        gg += swzl<0x201F>(gg);
        go += swzl<0x201F>(go);

        const float i2 = sigm(gi), f2 = sigm(gf), g2 = tanh_(gg), o2 = sigm(go);
        c2 = f2 * c2 + i2 * g2;
        const float h2n = o2 * tanh_(c2);

        if (ks < 8) {  // unique (b=ks, d2) owner accumulates FC
            const float4* wq = (const float4*)(wsc + (t * 64 + d2) * 12);
            const float4 q0 = wq[0], q1 = wq[1], q2 = wq[2];
            facc[0] += h2n * q0.x; facc[1] += h2n * q0.y; facc[2] += h2n * q0.z; facc[3] += h2n * q0.w;
            facc[4] += h2n * q1.x; facc[5] += h2n * q1.y; facc[6] += h2n * q1.z; facc[7] += h2n * q1.w;
            facc[8] += h2n * q2.x; facc[9] += h2n * q2.y; facc[10] += h2n * q2.z;
        }
        __syncthreads();                       // reads of lh1t[buf], lh2 done
        if (do_stage)
            *(float4*)((char*)lh1t + nbufoff + (bs * 33 + k4) * 16) = stg;
        lh2[ksl * 64 + d2] = h2n;              // ks and ks+8 write identical value
        __syncthreads();                       // staged tile + new lh2 visible
    };

    for (int th = 0; th < TSTEPS / 2; ++th) {
        step(2 * th, 0, 4224);
        step(2 * th + 1, 4224, 0);
    }

    // FC reduction: sum facc over the wave's 4 d2 values (lane bits 4,5)
#pragma unroll
    for (int c = 0; c < NCLS; ++c) {
        float v = facc[c];
        v += __shfl_xor(v, 16);
        v += __shfl_xor(v, 32);
        facc[c] = v;
    }
    const int w = tid >> 6;
    if ((tid & 63) < 8) {                      // lane = ks < 8, d2-subgroup 0
#pragma unroll
        for (int c = 0; c < NCLS; ++c) gfc[w * 88 + ks * 11 + c] = facc[c];
    }
    __syncthreads();
    if (tid < 88) {
        const int b = tid / 11, c = tid % 11;
        float s = bfc[c];
#pragma unroll
        for (int w2 = 0; w2 < 16; ++w2) s += gfc[w2 * 88 + b * 11 + c];
        out[(b0 + b) * 11 + c] = s;
    }
}

extern "C" void kernel_launch(void* const* d_in, const int* in_sizes, int n_in,
                              void* d_out, int out_size, void* d_ws, size_t ws_size,
                              hipStream_t stream) {
    const float* x    = (const float*)d_in[0];
    const float* Wih1 = (const float*)d_in[1];
    const float* Whh1 = (const float*)d_in[2];
    const float* Wih2 = (const float*)d_in[3];
    const float* Whh2 = (const float*)d_in[4];
    const float* Wfc  = (const float*)d_in[5];
    const float* bfc  = (const float*)d_in[6];
    float* out = (float*)d_out;
    float* ws  = (float*)d_ws;

    prep<<<(212992 + 255) / 256, 256, 0, stream>>>(Whh1, Wih2, Whh2, Wfc, ws);
    lstm_l1<<<256, 1024, 0, stream>>>(x, Wih1, ws);
    lstm_l2<<<256, 1024, 0, stream>>>(bfc, ws, out);
}